// Round 1
// baseline (93.450 us; speedup 1.0000x reference)
//
#include <hip/hip_runtime.h>

#define ND 1024
#define NNE (ND*ND)

typedef __bf16 bf16x8 __attribute__((ext_vector_type(8)));
typedef float f32x4 __attribute__((ext_vector_type(4)));

__device__ __forceinline__ unsigned short f2bf(float f) {
  unsigned u = __float_as_uint(f);
  u += 0x7fffu + ((u >> 16) & 1u);
  return (unsigned short)(u >> 16);
}

__device__ __forceinline__ void gload_lds16(const void* g, void* l) {
  __builtin_amdgcn_global_load_lds(
      (const __attribute__((address_space(1))) void*)g,
      (__attribute__((address_space(3))) void*)l, 16, 0, 0);
}

// ---- convert x (256x1024 f32) -> bf16 ----
__global__ void convert_x_kernel(const float* __restrict__ x, unsigned short* __restrict__ xb) {
  int i = blockIdx.x * blockDim.x + threadIdx.x;   // one float4 each, 65536 total
  float4 v = reinterpret_cast<const float4*>(x)[i];
  ushort4 o;
  o.x = f2bf(v.x); o.y = f2bf(v.y); o.z = f2bf(v.z); o.w = f2bf(v.w);
  reinterpret_cast<ushort4*>(xb)[i] = o;
}

// ---- transpose+convert psi: out[j][m][n] = bf16(psi[j][n][m]) ----
__global__ void psi_transpose_kernel(const float* __restrict__ psi, unsigned short* __restrict__ out) {
  __shared__ float t[32][33];
  int blk = blockIdx.x;            // j*1024 + tn*32 + tm
  int j  = blk >> 10;
  int tn = (blk >> 5) & 31;
  int tm = blk & 31;
  const float* src = psi + ((size_t)j << 20) + (size_t)(tn << 5) * ND + (tm << 5);
  int r  = threadIdx.x >> 3;       // 0..31
  int c4 = (threadIdx.x & 7) << 2; // 0,4,...,28
  float4 v = *reinterpret_cast<const float4*>(src + (size_t)r * ND + c4);
  t[r][c4 + 0] = v.x; t[r][c4 + 1] = v.y; t[r][c4 + 2] = v.z; t[r][c4 + 3] = v.w;
  __syncthreads();
  // write rows m = tm*32 + r, cols n = tn*32 + c4..c4+3
  ushort4 o;
  o.x = f2bf(t[c4 + 0][r]);
  o.y = f2bf(t[c4 + 1][r]);
  o.z = f2bf(t[c4 + 2][r]);
  o.w = f2bf(t[c4 + 3][r]);
  unsigned short* dst = out + ((size_t)j << 20) + (size_t)((tm << 5) + r) * ND + (tn << 5) + c4;
  *reinterpret_cast<ushort4*>(dst) = o;
}

// ---- phi order 0: phi[b,f,0] = sum_n x[b,f,n]*lowpass[n] ----
__global__ void phi0_kernel(const float* __restrict__ x, const float* __restrict__ lp,
                            float* __restrict__ phi) {
  int w = threadIdx.x >> 6, lane = threadIdx.x & 63;
  int row = blockIdx.x * 4 + w;    // 0..255
  const float* xr = x + (size_t)row * ND;
  float s = 0.f;
  for (int i = lane * 4; i < ND; i += 256) {
    float4 v = *reinterpret_cast<const float4*>(xr + i);
    float4 l = *reinterpret_cast<const float4*>(lp + i);
    s += v.x * l.x + v.y * l.y + v.z * l.z + v.w * l.w;
  }
  #pragma unroll
  for (int off = 32; off; off >>= 1) s += __shfl_xor(s, off);
  if (lane == 0) phi[row * 73] = s;
}

// ---- fused scattering GEMM ----
// A: M x 1024 bf16 row-major. BT: psi^T bf16, J x 1024 x 1024 (row = output col m).
// C = |A @ psi[j]| ; LAYER==1 stores S1 and accumulates phi[...,1+j];
// LAYER==2 accumulates phi[...,9+k*8+j] only.
template<int BM, int BN, int LAYER>
__global__ __launch_bounds__(256)
void gemm_scat(const unsigned short* __restrict__ A,
               const unsigned short* __restrict__ BT,
               const float* __restrict__ lowpass,
               unsigned short* __restrict__ Sout,
               float* __restrict__ phi) {
  constexpr int BK = 64;
  constexpr int WM = BM / 2, WN = BN / 2;
  constexpr int MF = WM / 16, NF = WN / 16;
  static_assert(BM % 32 == 0 && BN % 32 == 0, "");

  __shared__ __align__(16) unsigned short Asm[BM * BK];
  __shared__ __align__(16) unsigned short Bsm[BN * BK];

  const int tid  = threadIdx.x;
  const int lane = tid & 63;
  const int w    = tid >> 6;
  const int wrow = w >> 1, wcol = w & 1;

  const int j    = blockIdx.z;
  const int row0 = blockIdx.y * BM;
  const int n0   = blockIdx.x * BN;

  const unsigned short* Bj = BT + (size_t)j * NNE;

  f32x4 acc[MF][NF] = {};

  constexpr int ACH = BM * 8;   // 16B chunks in A tile (8 per 64-elem row)
  constexpr int BCH = BN * 8;

  for (int k0 = 0; k0 < ND; k0 += BK) {
    __syncthreads();
    #pragma unroll
    for (int p = 0; p < ACH / 256; ++p) {
      int c = p * 256 + tid;
      int r = c >> 3;
      int s = (c & 7) ^ (r & 7);                       // pre-swizzled source slot
      gload_lds16(A + (size_t)(row0 + r) * ND + k0 + s * 8, Asm + c * 8);
    }
    #pragma unroll
    for (int p = 0; p < BCH / 256; ++p) {
      int c = p * 256 + tid;
      int r = c >> 3;
      int s = (c & 7) ^ (r & 7);
      gload_lds16(Bj + (size_t)(n0 + r) * ND + k0 + s * 8, Bsm + c * 8);
    }
    __syncthreads();

    #pragma unroll
    for (int kk = 0; kk < 2; ++kk) {
      bf16x8 a[MF], b[NF];
      int srd = kk * 4 + (lane >> 4);                  // logical 16B slot
      #pragma unroll
      for (int m = 0; m < MF; ++m) {
        int r = wrow * WM + m * 16 + (lane & 15);
        a[m] = *reinterpret_cast<const bf16x8*>(&Asm[r * 64 + ((srd ^ (r & 7)) * 8)]);
      }
      #pragma unroll
      for (int n = 0; n < NF; ++n) {
        int r = wcol * WN + n * 16 + (lane & 15);
        b[n] = *reinterpret_cast<const bf16x8*>(&Bsm[r * 64 + ((srd ^ (r & 7)) * 8)]);
      }
      #pragma unroll
      for (int m = 0; m < MF; ++m)
        #pragma unroll
        for (int n = 0; n < NF; ++n)
          acc[m][n] = __builtin_amdgcn_mfma_f32_16x16x32_bf16(a[m], b[n], acc[m][n], 0, 0, 0);
    }
  }

  // ---- epilogue: abs, optional S1 store, fused lowpass row-reduction ----
  float lp[NF];
  #pragma unroll
  for (int n = 0; n < NF; ++n)
    lp[n] = lowpass[n0 + wcol * WN + n * 16 + (lane & 15)];

  #pragma unroll
  for (int m = 0; m < MF; ++m) {
    #pragma unroll
    for (int r = 0; r < 4; ++r) {
      int rg = row0 + wrow * WM + m * 16 + (lane >> 4) * 4 + r;
      float psum = 0.f;
      #pragma unroll
      for (int n = 0; n < NF; ++n) {
        float v = fabsf(acc[m][n][r]);
        psum += v * lp[n];
        if (LAYER == 1) {
          int colg = n0 + wcol * WN + n * 16 + (lane & 15);
          size_t si = ((size_t)((rg >> 4) * 8 + j) * 16 + (rg & 15)) * ND + colg;
          Sout[si] = f2bf(v);
        }
      }
      psum += __shfl_xor(psum, 1);
      psum += __shfl_xor(psum, 2);
      psum += __shfl_xor(psum, 4);
      psum += __shfl_xor(psum, 8);
      if ((lane & 15) == 0) {
        int pidx;
        if (LAYER == 1) pidx = rg * 73 + 1 + j;
        else            pidx = ((rg >> 7) * 16 + (rg & 15)) * 73 + 9 + ((rg >> 4) & 7) * 8 + j;
        atomicAdd(&phi[pidx], psum);
      }
    }
  }
}

extern "C" void kernel_launch(void* const* d_in, const int* in_sizes, int n_in,
                              void* d_out, int out_size, void* d_ws, size_t ws_size,
                              hipStream_t stream) {
  (void)in_sizes; (void)n_in; (void)ws_size;
  const float* x       = (const float*)d_in[0];
  const float* psi     = (const float*)d_in[1];
  const float* lowpass = (const float*)d_in[2];
  float* phi = (float*)d_out;

  unsigned short* xb   = (unsigned short*)d_ws;                        // 512 KB
  unsigned short* psiT = (unsigned short*)((char*)d_ws + (1u << 20));  // 16 MB
  unsigned short* S1   = (unsigned short*)((char*)d_ws + (18u << 20)); // 4 MB

  hipMemsetAsync(d_out, 0, sizeof(float) * (size_t)out_size, stream);

  convert_x_kernel<<<256, 256, 0, stream>>>(x, xb);
  psi_transpose_kernel<<<8192, 256, 0, stream>>>(psi, psiT);
  phi0_kernel<<<64, 256, 0, stream>>>(x, lowpass, phi);

  // layer 1: M=256 rows (b*16+f), tiles 64x128 -> grid (8, 4, 8)
  gemm_scat<64, 128, 1><<<dim3(8, 4, 8), 256, 0, stream>>>(xb, psiT, lowpass, S1, phi);
  // layer 2: M=2048 rows ((b*8+k)*16+f), tiles 128x128 -> grid (8, 16, 8)
  gemm_scat<128, 128, 2><<<dim3(8, 16, 8), 256, 0, stream>>>(S1, psiT, lowpass, nullptr, phi);
}